// Round 4
// baseline (601.408 us; speedup 1.0000x reference)
//
#include <hip/hip_runtime.h>
#include <math.h>

#define NROWS 65536
#define DIM 256
#define KC 1024
#define FCAP1 16384
#define FCAP2 4096
#define MARGIN1 0.024f
#define MARGIN2 5.0e-5f

typedef float  floatx4 __attribute__((ext_vector_type(4)));
typedef short  shortx8 __attribute__((ext_vector_type(8)));

__device__ __forceinline__ unsigned short f2bf(float f) {
    unsigned u = __float_as_uint(f);
    return (unsigned short)((u + 0x7fffu + ((u >> 16) & 1u)) >> 16);
}
__device__ __forceinline__ float bf2f(unsigned short h) {
    return __uint_as_float(((unsigned)h) << 16);
}
// monotone float->u32 mapping (works for negatives)
__device__ __forceinline__ unsigned fmap(float s) {
    unsigned u = __float_as_uint(s);
    return u ^ (unsigned)(((int)u >> 31) | 0x80000000);
}
__device__ __forceinline__ float funmap(unsigned m) {
    unsigned u = (m & 0x80000000u) ? (m ^ 0x80000000u) : ~m;
    return __uint_as_float(u);
}
#define UMIN(a, b) ((a) < (b) ? (a) : (b))

// ---------------------------------------------------------------------------
// Kernel 1: row norms for X (xn) and E (en); bf16-convert E -> Eb; zero
// loss accum + flag counters. One 64-lane wave per row.
// ---------------------------------------------------------------------------
__global__ void __launch_bounds__(256) vq_norms(const float* __restrict__ x,
                                                const float* __restrict__ e,
                                                float* __restrict__ xn,
                                                float* __restrict__ en,
                                                unsigned short* __restrict__ Eb,
                                                float* __restrict__ accum,
                                                int* __restrict__ flagCnt) {
    if (blockIdx.x == 0 && threadIdx.x == 0) {
        *accum = 0.0f; flagCnt[0] = 0; flagCnt[1] = 0;
    }
    const int wave = threadIdx.x >> 6;
    const int lane = threadIdx.x & 63;
    const int row = blockIdx.x * 4 + wave;   // grid = (NROWS+KC)/4 exactly
    const float* src;
    float* dst;
    bool isE = (row >= NROWS);
    int er = row - NROWS;
    if (!isE) { src = x + (size_t)row * DIM; dst = xn + row; }
    else      { src = e + (size_t)er * DIM; dst = en + er; }
    float4 v = ((const float4*)src)[lane];
    if (isE) {
        ushort4 o; o.x = f2bf(v.x); o.y = f2bf(v.y); o.z = f2bf(v.z); o.w = f2bf(v.w);
        ((ushort4*)(Eb + (size_t)er * DIM))[lane] = o;
    }
    float s = (v.x * v.x + v.y * v.y) + (v.z * v.z + v.w * v.w);
#pragma unroll
    for (int off = 1; off < 64; off <<= 1)
        s += __shfl_xor(s, off, 64);
    if (lane == 0) *dst = s;
}

// ---------------------------------------------------------------------------
// Kernel 2 (pass1): bf16 MFMA distance-GEMM + argmin over all rows.
// Block = 256 thr / 4 waves; wave owns 32 rows (2 m-tiles of 16), block 128.
// Grid 512 covers all rows; each block sweeps all 1024 codes in 32-code
// tiles (E-tile double-buffered through LDS, padded stride 264 halfs =
// 132 dw == 4 mod 32 -> conflict-free ds_read_b128 b-frags).
// A-fragments: converted fp32->bf16 in registers, X read once from HBM.
// mfma 16x16x32_bf16; C/D: col=lane&15, row=(lane>>4)*4+reg (HW-verified).
// Tracks per-row best + second-best approx score; rows with gap < MARGIN1
// are appended to flagList1 for the 3-product refinement pass.
// ---------------------------------------------------------------------------
__global__ void __launch_bounds__(256) vq_pass1(const float* __restrict__ X,
                                                const unsigned short* __restrict__ Eb,
                                                const float* __restrict__ en,
                                                unsigned long long* __restrict__ packed,
                                                int* __restrict__ flagCnt,
                                                int* __restrict__ flagList1) {
    __shared__ unsigned short Bs[2][32][264];   // 33792 B, dbl-buffered E-tile

    const int tid = threadIdx.x;
    const int w   = tid >> 6;
    const int l   = tid & 63;
    const int l4  = l >> 4;      // quad 0..3
    const int l15 = l & 15;
    const int rowBase = blockIdx.x * 128;
    const int waveRow = rowBase + w * 32;

    // ---- A preload: 2 m-tiles x 8 k-steps, fp32 -> bf16 in regs (64 VGPR)
    shortx8 A[2][8];
#pragma unroll
    for (int mt = 0; mt < 2; mt++) {
        const float* xp = X + (size_t)(waveRow + mt * 16 + l15) * DIM + l4 * 8;
#pragma unroll
        for (int kt = 0; kt < 8; kt++) {
            float4 p = *(const float4*)(xp + kt * 32);
            float4 q = *(const float4*)(xp + kt * 32 + 4);
            shortx8 v;
            v[0] = (short)f2bf(p.x); v[1] = (short)f2bf(p.y);
            v[2] = (short)f2bf(p.z); v[3] = (short)f2bf(p.w);
            v[4] = (short)f2bf(q.x); v[5] = (short)f2bf(q.y);
            v[6] = (short)f2bf(q.z); v[7] = (short)f2bf(q.w);
            A[mt][kt] = v;
        }
    }

    // staging role: thread -> (code sc, 64B segment sseg)
    const int sc = tid & 31;
    const int sseg = tid >> 5;
    uint4 st0, st1, st2, st3;
    {   // prologue: stage tile 0 into buf 0
        const uint4* src = (const uint4*)(Eb + (size_t)sc * DIM + sseg * 32);
        st0 = src[0]; st1 = src[1]; st2 = src[2]; st3 = src[3];
        uint4* dst = (uint4*)&Bs[0][sc][sseg * 32];
        dst[0] = st0; dst[1] = st1; dst[2] = st2; dst[3] = st3;
    }

    unsigned long long best[8];
    unsigned bsec[8];
#pragma unroll
    for (int i = 0; i < 8; i++) { best[i] = ~0ull; bsec[i] = 0xFFFFFFFFu; }

    for (int ct = 0; ct < 32; ct++) {
        const int cur = ct & 1, nxt = cur ^ 1;
        __syncthreads();
        bool doNext = (ct + 1 < 32);
        if (doNext) {
            const uint4* src = (const uint4*)(Eb + (size_t)((ct + 1) * 32 + sc) * DIM + sseg * 32);
            st0 = src[0]; st1 = src[1]; st2 = src[2]; st3 = src[3];
        }
        float en0 = en[ct * 32 + l15];
        float en1 = en[ct * 32 + 16 + l15];

        floatx4 acc[2][2];
#pragma unroll
        for (int mt = 0; mt < 2; mt++)
#pragma unroll
            for (int nt = 0; nt < 2; nt++)
                acc[mt][nt] = (floatx4){0.f, 0.f, 0.f, 0.f};

#pragma unroll
        for (int kt = 0; kt < 8; kt++) {
            shortx8 b0 = *(const shortx8*)&Bs[cur][l15][kt * 32 + l4 * 8];
            shortx8 b1 = *(const shortx8*)&Bs[cur][16 + l15][kt * 32 + l4 * 8];
            acc[0][0] = __builtin_amdgcn_mfma_f32_16x16x32_bf16(A[0][kt], b0, acc[0][0], 0, 0, 0);
            acc[0][1] = __builtin_amdgcn_mfma_f32_16x16x32_bf16(A[0][kt], b1, acc[0][1], 0, 0, 0);
            acc[1][0] = __builtin_amdgcn_mfma_f32_16x16x32_bf16(A[1][kt], b0, acc[1][0], 0, 0, 0);
            acc[1][1] = __builtin_amdgcn_mfma_f32_16x16x32_bf16(A[1][kt], b1, acc[1][1], 0, 0, 0);
        }

        // epilogue: fold this code-tile into per-row best/second
#pragma unroll
        for (int mt = 0; mt < 2; mt++)
#pragma unroll
            for (int nt = 0; nt < 2; nt++) {
                float enc = nt ? en1 : en0;
                unsigned code = (unsigned)(ct * 32 + nt * 16 + l15);
#pragma unroll
                for (int r = 0; r < 4; r++) {
                    float s = fmaf(-2.0f, acc[mt][nt][r], enc);
                    unsigned m = fmap(s);
                    unsigned long long p = ((unsigned long long)m << 32) | code;
                    int sl = mt * 4 + r;
                    if (p < best[sl]) {
                        bsec[sl] = UMIN(bsec[sl], (unsigned)(best[sl] >> 32));
                        best[sl] = p;
                    } else {
                        bsec[sl] = UMIN(bsec[sl], m);
                    }
                }
            }

        if (doNext) {
            uint4* dst = (uint4*)&Bs[nxt][sc][sseg * 32];
            dst[0] = st0; dst[1] = st1; dst[2] = st2; dst[3] = st3;
        }
    }

    // ---- cross-lane reduction (reuse Bs as scratch: 16KB u64 + 8KB u32)
    __syncthreads();
    unsigned long long* V = (unsigned long long*)&Bs[0][0][0];
    unsigned* W = (unsigned*)(V + 2048);
#pragma unroll
    for (int sl = 0; sl < 8; sl++) {
        int mt = sl >> 2, r = sl & 3;
        int rl = mt * 16 + l4 * 4 + r;
        V[(w * 32 + rl) * 16 + l15] = best[sl];
        W[(w * 32 + rl) * 16 + l15] = bsec[sl];
    }
    __syncthreads();
    if (tid < 128) {
        unsigned long long b1 = ~0ull;
        unsigned b2 = 0xFFFFFFFFu;
        const unsigned long long* Vp = V + tid * 16;
        const unsigned* Wp = W + tid * 16;
#pragma unroll
        for (int i = 0; i < 16; i++) {
            unsigned long long v = Vp[i];
            unsigned wv = Wp[i];
            if (v < b1) {
                b2 = UMIN(b2, (unsigned)(b1 >> 32));
                b1 = v;
                b2 = UMIN(b2, wv);
            } else {
                b2 = UMIN(b2, (unsigned)(v >> 32));
            }
        }
        int row = rowBase + tid;
        packed[row] = b1;
        float s1 = funmap((unsigned)(b1 >> 32));
        float s2 = funmap(b2);
        if (s2 - s1 < MARGIN1) {
            int pos = atomicAdd(&flagCnt[0], 1);
            if (pos < FCAP1) flagList1[pos] = row;
        }
    }
}

// ---------------------------------------------------------------------------
// Kernel 3 (pass2): 3-product bf16-split MFMA (xh*eh + xh*el + xl*eh) on
// pass1-flagged rows only. Same tile structure; A (hi+lo) from fp32 X via
// rowMap; E staged fp32->hi/lo bf16 tiles. Rows with refined gap < MARGIN2
// go to flagList2 for the exact pass.
// ---------------------------------------------------------------------------
__global__ void __launch_bounds__(256) vq_pass2(const float* __restrict__ X,
                                                const float* __restrict__ E,
                                                const float* __restrict__ en,
                                                unsigned long long* __restrict__ packed,
                                                int* __restrict__ flagCnt,
                                                const int* __restrict__ flagList1,
                                                int* __restrict__ flagList2) {
    __shared__ unsigned short BsH[2][32][264];
    __shared__ unsigned short BsL[2][32][264];

    int cnt = flagCnt[0];
    if (cnt > FCAP1) cnt = FCAP1;
    const int base = blockIdx.x * 128;
    if (base >= cnt) return;

    const int tid = threadIdx.x;
    const int w = tid >> 6, l = tid & 63;
    const int l4 = l >> 4, l15 = l & 15;

    // ---- A preload (hi+lo) via row indirection
    shortx8 Ah[2][8], Al[2][8];
#pragma unroll
    for (int mt = 0; mt < 2; mt++) {
        int j = base + w * 32 + mt * 16 + l15;
        int row = flagList1[j < cnt ? j : cnt - 1];
        const float* xp = X + (size_t)row * DIM + l4 * 8;
#pragma unroll
        for (int kt = 0; kt < 8; kt++) {
            shortx8 vh, vl;
#pragma unroll
            for (int c4 = 0; c4 < 2; c4++) {
                float4 p = *(const float4*)(xp + kt * 32 + c4 * 4);
                float f[4] = {p.x, p.y, p.z, p.w};
#pragma unroll
                for (int q = 0; q < 4; q++) {
                    unsigned short h = f2bf(f[q]);
                    vh[c4 * 4 + q] = (short)h;
                    vl[c4 * 4 + q] = (short)f2bf(f[q] - bf2f(h));
                }
            }
            Ah[mt][kt] = vh; Al[mt][kt] = vl;
        }
    }

    const int sc = tid & 31;
    const int sseg = tid >> 5;

    // stage helper (fp32 E -> hi/lo bf16 tiles), done inline twice
#define STAGE_P2(CT, BUF)                                                          \
    {                                                                              \
        const float* src = E + (size_t)((CT) * 32 + sc) * DIM + sseg * 32;         \
        _Pragma("unroll")                                                          \
        for (int h2 = 0; h2 < 2; h2++) {                                           \
            unsigned hh[8], ll[8];                                                 \
            _Pragma("unroll")                                                      \
            for (int d2 = 0; d2 < 8; d2++) {                                       \
                float a0 = src[h2 * 16 + d2 * 2];                                  \
                float a1 = src[h2 * 16 + d2 * 2 + 1];                              \
                unsigned short h0 = f2bf(a0), h1 = f2bf(a1);                       \
                unsigned short l0 = f2bf(a0 - bf2f(h0)), l1 = f2bf(a1 - bf2f(h1)); \
                hh[d2] = (unsigned)h0 | ((unsigned)h1 << 16);                      \
                ll[d2] = (unsigned)l0 | ((unsigned)l1 << 16);                      \
            }                                                                      \
            uint4* dh = (uint4*)&BsH[BUF][sc][sseg * 32 + h2 * 16];                \
            dh[0] = (uint4){hh[0], hh[1], hh[2], hh[3]};                           \
            dh[1] = (uint4){hh[4], hh[5], hh[6], hh[7]};                           \
            uint4* dl = (uint4*)&BsL[BUF][sc][sseg * 32 + h2 * 16];                \
            dl[0] = (uint4){ll[0], ll[1], ll[2], ll[3]};                           \
            dl[1] = (uint4){ll[4], ll[5], ll[6], ll[7]};                           \
        }                                                                          \
    }

    STAGE_P2(0, 0)

    unsigned long long best[8];
    unsigned bsec[8];
#pragma unroll
    for (int i = 0; i < 8; i++) { best[i] = ~0ull; bsec[i] = 0xFFFFFFFFu; }

    for (int ct = 0; ct < 32; ct++) {
        const int cur = ct & 1, nxt = cur ^ 1;
        __syncthreads();
        float en0 = en[ct * 32 + l15];
        float en1 = en[ct * 32 + 16 + l15];

        floatx4 acc[2][2];
#pragma unroll
        for (int mt = 0; mt < 2; mt++)
#pragma unroll
            for (int nt = 0; nt < 2; nt++)
                acc[mt][nt] = (floatx4){0.f, 0.f, 0.f, 0.f};

#pragma unroll
        for (int kt = 0; kt < 8; kt++) {
            shortx8 bh0 = *(const shortx8*)&BsH[cur][l15][kt * 32 + l4 * 8];
            shortx8 bh1 = *(const shortx8*)&BsH[cur][16 + l15][kt * 32 + l4 * 8];
            shortx8 bl0 = *(const shortx8*)&BsL[cur][l15][kt * 32 + l4 * 8];
            shortx8 bl1 = *(const shortx8*)&BsL[cur][16 + l15][kt * 32 + l4 * 8];
#pragma unroll
            for (int mt = 0; mt < 2; mt++) {
                acc[mt][0] = __builtin_amdgcn_mfma_f32_16x16x32_bf16(Ah[mt][kt], bh0, acc[mt][0], 0, 0, 0);
                acc[mt][0] = __builtin_amdgcn_mfma_f32_16x16x32_bf16(Ah[mt][kt], bl0, acc[mt][0], 0, 0, 0);
                acc[mt][0] = __builtin_amdgcn_mfma_f32_16x16x32_bf16(Al[mt][kt], bh0, acc[mt][0], 0, 0, 0);
                acc[mt][1] = __builtin_amdgcn_mfma_f32_16x16x32_bf16(Ah[mt][kt], bh1, acc[mt][1], 0, 0, 0);
                acc[mt][1] = __builtin_amdgcn_mfma_f32_16x16x32_bf16(Ah[mt][kt], bl1, acc[mt][1], 0, 0, 0);
                acc[mt][1] = __builtin_amdgcn_mfma_f32_16x16x32_bf16(Al[mt][kt], bh1, acc[mt][1], 0, 0, 0);
            }
        }

#pragma unroll
        for (int mt = 0; mt < 2; mt++)
#pragma unroll
            for (int nt = 0; nt < 2; nt++) {
                float enc = nt ? en1 : en0;
                unsigned code = (unsigned)(ct * 32 + nt * 16 + l15);
#pragma unroll
                for (int r = 0; r < 4; r++) {
                    float s = fmaf(-2.0f, acc[mt][nt][r], enc);
                    unsigned m = fmap(s);
                    unsigned long long p = ((unsigned long long)m << 32) | code;
                    int sl = mt * 4 + r;
                    if (p < best[sl]) {
                        bsec[sl] = UMIN(bsec[sl], (unsigned)(best[sl] >> 32));
                        best[sl] = p;
                    } else {
                        bsec[sl] = UMIN(bsec[sl], m);
                    }
                }
            }

        if (ct + 1 < 32) STAGE_P2(ct + 1, nxt)
    }

    __syncthreads();
    unsigned long long* V = (unsigned long long*)&BsH[0][0][0];
    unsigned* W = (unsigned*)(V + 2048);
#pragma unroll
    for (int sl = 0; sl < 8; sl++) {
        int mt = sl >> 2, r = sl & 3;
        int rl = mt * 16 + l4 * 4 + r;
        V[(w * 32 + rl) * 16 + l15] = best[sl];
        W[(w * 32 + rl) * 16 + l15] = bsec[sl];
    }
    __syncthreads();
    if (tid < 128 && base + tid < cnt) {
        unsigned long long b1 = ~0ull;
        unsigned b2 = 0xFFFFFFFFu;
        const unsigned long long* Vp = V + tid * 16;
        const unsigned* Wp = W + tid * 16;
#pragma unroll
        for (int i = 0; i < 16; i++) {
            unsigned long long v = Vp[i];
            unsigned wv = Wp[i];
            if (v < b1) {
                b2 = UMIN(b2, (unsigned)(b1 >> 32));
                b1 = v;
                b2 = UMIN(b2, wv);
            } else {
                b2 = UMIN(b2, (unsigned)(v >> 32));
            }
        }
        int row = flagList1[base + tid];
        packed[row] = b1;
        float s1 = funmap((unsigned)(b1 >> 32));
        float s2 = funmap(b2);
        if (s2 - s1 < MARGIN2) {
            int pos = atomicAdd(&flagCnt[1], 1);
            if (pos < FCAP2) flagList2[pos] = row;
        }
    }
#undef STAGE_P2
}

// ---------------------------------------------------------------------------
// Kernel 4 (pass3): exact fp32 re-solve for pass2-flagged rows (~O(10)).
// Block per row; thread per code (4 codes each). Replicates np rounding:
// s = fmaf(-2, dot, xn+en); first-index tie-break via packed u64 min.
// ---------------------------------------------------------------------------
__global__ void __launch_bounds__(256) vq_pass3(const float* __restrict__ X,
                                                const float* __restrict__ E,
                                                const float* __restrict__ xn,
                                                const float* __restrict__ en,
                                                unsigned long long* __restrict__ packed,
                                                const int* __restrict__ flagCnt2,
                                                const int* __restrict__ flagList2) {
    __shared__ float xs[256];
    __shared__ unsigned long long red[256];
    int cnt = *flagCnt2;
    if (cnt > FCAP2) cnt = FCAP2;
    const int tid = threadIdx.x;

    for (int it = blockIdx.x; it < cnt; it += gridDim.x) {
        int row = flagList2[it];
        __syncthreads();
        if (tid < 64)
            *(float4*)&xs[tid * 4] = *(const float4*)&X[(size_t)row * DIM + tid * 4];
        __syncthreads();
        float xnr = xn[row];
        unsigned long long bl = ~0ull;
#pragma unroll
        for (int cc = 0; cc < 4; cc++) {
            int c = tid + cc * 256;
            const float* ep = E + (size_t)c * DIM;
            float dot = 0.0f;
            for (int d = 0; d < 256; d += 32) {
#pragma unroll
                for (int dd = 0; dd < 32; dd += 4) {
                    float4 e4 = *(const float4*)(ep + d + dd);
                    float4 x4 = *(const float4*)(xs + d + dd);
                    dot = fmaf(x4.x, e4.x, dot);
                    dot = fmaf(x4.y, e4.y, dot);
                    dot = fmaf(x4.z, e4.z, dot);
                    dot = fmaf(x4.w, e4.w, dot);
                }
            }
            float s = fmaf(-2.0f, dot, xnr + en[c]);   // matches np rounding
            unsigned long long p = ((unsigned long long)__float_as_uint(s) << 32) | (unsigned)c;
            if (p < bl) bl = p;
        }
        red[tid] = bl;
        __syncthreads();
        if (tid == 0) {
            unsigned long long m = red[0];
            for (int i = 1; i < 256; i++)
                if (red[i] < m) m = red[i];
            packed[row] = m;
        }
    }
}

// ---------------------------------------------------------------------------
// Kernel 5: gather quantized rows + fused squared-diff partial sums.
// ---------------------------------------------------------------------------
__global__ void __launch_bounds__(256) vq_gather(const float* __restrict__ X,
                                                 const float* __restrict__ E,
                                                 const unsigned long long* __restrict__ packed,
                                                 float* __restrict__ out,
                                                 float* __restrict__ accum) {
    const int tid = threadIdx.x;
    const int wave = tid >> 6;
    const int lane = tid & 63;
    const size_t rowBase = (size_t)blockIdx.x * 16;
    float part = 0.0f;
#pragma unroll
    for (int rr = 0; rr < 4; rr++) {
        size_t row = rowBase + wave + rr * 4;
        int code = (int)(unsigned int)(packed[row] & 0xffffffffull);
        float4 q = ((const float4*)(E + (size_t)code * DIM))[lane];
        float4 xv = ((const float4*)(X + row * DIM))[lane];
        ((float4*)(out + row * DIM))[lane] = q;
        float dx = q.x - xv.x, dy = q.y - xv.y, dz = q.z - xv.z, dw = q.w - xv.w;
        part = fmaf(dx, dx, part);
        part = fmaf(dy, dy, part);
        part = fmaf(dz, dz, part);
        part = fmaf(dw, dw, part);
    }
#pragma unroll
    for (int off = 1; off < 64; off <<= 1)
        part += __shfl_xor(part, off, 64);
    __shared__ float red[4];
    if ((tid & 63) == 0) red[tid >> 6] = part;
    __syncthreads();
    if (tid == 0) {
        float s = (red[0] + red[1]) + (red[2] + red[3]);
        atomicAdd(accum, s);
    }
}

// ---------------------------------------------------------------------------
// Kernel 6: finalize scalar loss. mean = sum / 2^24 (exact), loss = 2*mean.
// ---------------------------------------------------------------------------
__global__ void vq_finalize(const float* __restrict__ accum,
                            float* __restrict__ loss) {
    float m = *accum * (1.0f / 16777216.0f);
    *loss = m + m;
}

extern "C" void kernel_launch(void* const* d_in, const int* in_sizes, int n_in,
                              void* d_out, int out_size, void* d_ws, size_t ws_size,
                              hipStream_t stream) {
    const float* X = (const float*)d_in[0];   // [65536, 256]
    const float* E = (const float*)d_in[1];   // [1024, 256]
    float* out = (float*)d_out;               // quantized [65536*256] + loss [1]

    char* ws = (char*)d_ws;
    float* xn = (float*)ws;                                          // 262144 B
    float* en = (float*)(ws + 262144);                               //   4096 B
    unsigned short* Eb = (unsigned short*)(ws + 266240);             // 524288 B
    unsigned long long* packed = (unsigned long long*)(ws + 790528); // 524288 B
    int* flagList1 = (int*)(ws + 1314816);                           //  65536 B
    int* flagList2 = (int*)(ws + 1380352);                           //  16384 B
    float* accum = (float*)(ws + 1396736);
    int* flagCnt = (int*)(ws + 1396740);                             // [cnt1, cnt2]

    vq_norms   <<<(NROWS + KC) / 4, 256, 0, stream>>>(X, E, xn, en, Eb, accum, flagCnt);
    vq_pass1   <<<NROWS / 128, 256, 0, stream>>>(X, Eb, en, packed, flagCnt, flagList1);
    vq_pass2   <<<FCAP1 / 128, 256, 0, stream>>>(X, E, en, packed, flagCnt, flagList1, flagList2);
    vq_pass3   <<<64, 256, 0, stream>>>(X, E, xn, en, packed, flagCnt + 1, flagList2);
    vq_gather  <<<NROWS / 16, 256, 0, stream>>>(X, E, packed, out, accum);
    vq_finalize<<<1, 1, 0, stream>>>(accum, out + (size_t)NROWS * DIM);
}

// Round 5
// 348.571 us; speedup vs baseline: 1.7254x; 1.7254x over previous
//
#include <hip/hip_runtime.h>
#include <math.h>

#define NROWS 65536
#define DIM 256
#define KC 1024
#define FCAP1 16384
#define FCAP2 4096
#define MARGIN1 0.024f
#define MARGIN2 5.0e-5f

typedef float  floatx4 __attribute__((ext_vector_type(4)));
typedef short  shortx8 __attribute__((ext_vector_type(8)));

__device__ __forceinline__ unsigned short f2bf(float f) {
    unsigned u = __float_as_uint(f);
    return (unsigned short)((u + 0x7fffu + ((u >> 16) & 1u)) >> 16);
}
__device__ __forceinline__ float bf2f(unsigned short h) {
    return __uint_as_float(((unsigned)h) << 16);
}
// monotone float->u32 mapping (works for negatives)
__device__ __forceinline__ unsigned fmap(float s) {
    unsigned u = __float_as_uint(s);
    return u ^ (unsigned)(((int)u >> 31) | 0x80000000);
}
__device__ __forceinline__ float funmap(unsigned m) {
    unsigned u = (m & 0x80000000u) ? (m ^ 0x80000000u) : ~m;
    return __uint_as_float(u);
}
#define UMIN(a, b) ((a) < (b) ? (a) : (b))

// ---------------------------------------------------------------------------
// Kernel 1: row norms for X (xn) and E (en); E -> hi/lo bf16 split (EbH/EbL,
// precomputed here so pass2's staging is a pure coalesced copy); zero loss
// accum + flag counters. One 64-lane wave per row.
// ---------------------------------------------------------------------------
__global__ void __launch_bounds__(256) vq_norms(const float* __restrict__ x,
                                                const float* __restrict__ e,
                                                float* __restrict__ xn,
                                                float* __restrict__ en,
                                                unsigned short* __restrict__ EbH,
                                                unsigned short* __restrict__ EbL,
                                                float* __restrict__ accum,
                                                int* __restrict__ flagCnt) {
    if (blockIdx.x == 0 && threadIdx.x == 0) {
        *accum = 0.0f; flagCnt[0] = 0; flagCnt[1] = 0;
    }
    const int wave = threadIdx.x >> 6;
    const int lane = threadIdx.x & 63;
    const int row = blockIdx.x * 4 + wave;   // grid = (NROWS+KC)/4 exactly
    const float* src;
    float* dst;
    bool isE = (row >= NROWS);
    int er = row - NROWS;
    if (!isE) { src = x + (size_t)row * DIM; dst = xn + row; }
    else      { src = e + (size_t)er * DIM; dst = en + er; }
    float4 v = ((const float4*)src)[lane];
    if (isE) {
        ushort4 oh, ol;
        oh.x = f2bf(v.x); ol.x = f2bf(v.x - bf2f(oh.x));
        oh.y = f2bf(v.y); ol.y = f2bf(v.y - bf2f(oh.y));
        oh.z = f2bf(v.z); ol.z = f2bf(v.z - bf2f(oh.z));
        oh.w = f2bf(v.w); ol.w = f2bf(v.w - bf2f(oh.w));
        ((ushort4*)(EbH + (size_t)er * DIM))[lane] = oh;
        ((ushort4*)(EbL + (size_t)er * DIM))[lane] = ol;
    }
    float s = (v.x * v.x + v.y * v.y) + (v.z * v.z + v.w * v.w);
#pragma unroll
    for (int off = 1; off < 64; off <<= 1)
        s += __shfl_xor(s, off, 64);
    if (lane == 0) *dst = s;
}

// ---------------------------------------------------------------------------
// Kernel 2 (pass1): bf16 MFMA distance-GEMM + argmin over all rows.
// Block = 256 thr / 4 waves; wave owns 32 rows (2 m-tiles of 16), block 128.
// E-tile (32 codes) double-buffered through LDS, padded stride 264 halfs.
// A-fragments converted fp32->bf16 in registers (X read once from HBM).
// mfma 16x16x32_bf16; C/D: col=lane&15, row=(lane>>4)*4+reg (HW-verified).
// Tracks per-row best + second-best; rows with gap < MARGIN1 -> flagList1.
// ---------------------------------------------------------------------------
__global__ void __launch_bounds__(256) vq_pass1(const float* __restrict__ X,
                                                const unsigned short* __restrict__ EbH,
                                                const float* __restrict__ en,
                                                unsigned long long* __restrict__ packed,
                                                int* __restrict__ flagCnt,
                                                int* __restrict__ flagList1) {
    __shared__ unsigned short Bs[2][32][264];   // 33792 B, dbl-buffered E-tile

    const int tid = threadIdx.x;
    const int w   = tid >> 6;
    const int l   = tid & 63;
    const int l4  = l >> 4;      // quad 0..3
    const int l15 = l & 15;
    const int rowBase = blockIdx.x * 128;
    const int waveRow = rowBase + w * 32;

    shortx8 A[2][8];
#pragma unroll
    for (int mt = 0; mt < 2; mt++) {
        const float* xp = X + (size_t)(waveRow + mt * 16 + l15) * DIM + l4 * 8;
#pragma unroll
        for (int kt = 0; kt < 8; kt++) {
            float4 p = *(const float4*)(xp + kt * 32);
            float4 q = *(const float4*)(xp + kt * 32 + 4);
            shortx8 v;
            v[0] = (short)f2bf(p.x); v[1] = (short)f2bf(p.y);
            v[2] = (short)f2bf(p.z); v[3] = (short)f2bf(p.w);
            v[4] = (short)f2bf(q.x); v[5] = (short)f2bf(q.y);
            v[6] = (short)f2bf(q.z); v[7] = (short)f2bf(q.w);
            A[mt][kt] = v;
        }
    }

    const int sc = tid & 31;
    const int sseg = tid >> 5;
    uint4 st0, st1, st2, st3;
    {   // prologue: stage tile 0 into buf 0
        const uint4* src = (const uint4*)(EbH + (size_t)sc * DIM + sseg * 32);
        st0 = src[0]; st1 = src[1]; st2 = src[2]; st3 = src[3];
        uint4* dst = (uint4*)&Bs[0][sc][sseg * 32];
        dst[0] = st0; dst[1] = st1; dst[2] = st2; dst[3] = st3;
    }

    unsigned long long best[8];
    unsigned bsec[8];
#pragma unroll
    for (int i = 0; i < 8; i++) { best[i] = ~0ull; bsec[i] = 0xFFFFFFFFu; }

    for (int ct = 0; ct < 32; ct++) {
        const int cur = ct & 1, nxt = cur ^ 1;
        __syncthreads();
        bool doNext = (ct + 1 < 32);
        if (doNext) {
            const uint4* src = (const uint4*)(EbH + (size_t)((ct + 1) * 32 + sc) * DIM + sseg * 32);
            st0 = src[0]; st1 = src[1]; st2 = src[2]; st3 = src[3];
        }
        float en0 = en[ct * 32 + l15];
        float en1 = en[ct * 32 + 16 + l15];

        floatx4 acc[2][2];
#pragma unroll
        for (int mt = 0; mt < 2; mt++)
#pragma unroll
            for (int nt = 0; nt < 2; nt++)
                acc[mt][nt] = (floatx4){0.f, 0.f, 0.f, 0.f};

#pragma unroll
        for (int kt = 0; kt < 8; kt++) {
            shortx8 b0 = *(const shortx8*)&Bs[cur][l15][kt * 32 + l4 * 8];
            shortx8 b1 = *(const shortx8*)&Bs[cur][16 + l15][kt * 32 + l4 * 8];
            acc[0][0] = __builtin_amdgcn_mfma_f32_16x16x32_bf16(A[0][kt], b0, acc[0][0], 0, 0, 0);
            acc[0][1] = __builtin_amdgcn_mfma_f32_16x16x32_bf16(A[0][kt], b1, acc[0][1], 0, 0, 0);
            acc[1][0] = __builtin_amdgcn_mfma_f32_16x16x32_bf16(A[1][kt], b0, acc[1][0], 0, 0, 0);
            acc[1][1] = __builtin_amdgcn_mfma_f32_16x16x32_bf16(A[1][kt], b1, acc[1][1], 0, 0, 0);
        }

#pragma unroll
        for (int mt = 0; mt < 2; mt++)
#pragma unroll
            for (int nt = 0; nt < 2; nt++) {
                float enc = nt ? en1 : en0;
                unsigned code = (unsigned)(ct * 32 + nt * 16 + l15);
#pragma unroll
                for (int r = 0; r < 4; r++) {
                    float s = fmaf(-2.0f, acc[mt][nt][r], enc);
                    unsigned m = fmap(s);
                    unsigned long long p = ((unsigned long long)m << 32) | code;
                    int sl = mt * 4 + r;
                    if (p < best[sl]) {
                        bsec[sl] = UMIN(bsec[sl], (unsigned)(best[sl] >> 32));
                        best[sl] = p;
                    } else {
                        bsec[sl] = UMIN(bsec[sl], m);
                    }
                }
            }

        if (doNext) {
            uint4* dst = (uint4*)&Bs[nxt][sc][sseg * 32];
            dst[0] = st0; dst[1] = st1; dst[2] = st2; dst[3] = st3;
        }
    }

    __syncthreads();
    unsigned long long* V = (unsigned long long*)&Bs[0][0][0];
    unsigned* W = (unsigned*)(V + 2048);
#pragma unroll
    for (int sl = 0; sl < 8; sl++) {
        int mt = sl >> 2, r = sl & 3;
        int rl = mt * 16 + l4 * 4 + r;
        V[(w * 32 + rl) * 16 + l15] = best[sl];
        W[(w * 32 + rl) * 16 + l15] = bsec[sl];
    }
    __syncthreads();
    if (tid < 128) {
        unsigned long long b1 = ~0ull;
        unsigned b2 = 0xFFFFFFFFu;
        const unsigned long long* Vp = V + tid * 16;
        const unsigned* Wp = W + tid * 16;
#pragma unroll
        for (int i = 0; i < 16; i++) {
            unsigned long long v = Vp[i];
            unsigned wv = Wp[i];
            if (v < b1) {
                b2 = UMIN(b2, (unsigned)(b1 >> 32));
                b1 = v;
                b2 = UMIN(b2, wv);
            } else {
                b2 = UMIN(b2, (unsigned)(v >> 32));
            }
        }
        int row = rowBase + tid;
        packed[row] = b1;
        float s1 = funmap((unsigned)(b1 >> 32));
        float s2 = funmap(b2);
        if (s2 - s1 < MARGIN1) {
            int pos = atomicAdd(&flagCnt[0], 1);
            if (pos < FCAP1) flagList1[pos] = row;
        }
    }
}

// ---------------------------------------------------------------------------
// Kernel 3 (pass2): 3-product bf16-split MFMA (xh*eh + xh*el + xl*eh) on
// pass1-flagged rows only. E hi/lo tiles now staged from precomputed
// EbH/EbL via coalesced uint4 copies (R4's in-loop scalar fp32 conversion
// was a divergent-load latency disaster). Rows with refined gap < MARGIN2
// go to flagList2 for the exact pass.
// ---------------------------------------------------------------------------
__global__ void __launch_bounds__(256) vq_pass2(const float* __restrict__ X,
                                                const unsigned short* __restrict__ EbH,
                                                const unsigned short* __restrict__ EbL,
                                                const float* __restrict__ en,
                                                unsigned long long* __restrict__ packed,
                                                int* __restrict__ flagCnt,
                                                const int* __restrict__ flagList1,
                                                int* __restrict__ flagList2) {
    __shared__ unsigned short BsH[2][32][264];
    __shared__ unsigned short BsL[2][32][264];

    int cnt = flagCnt[0];
    if (cnt > FCAP1) cnt = FCAP1;
    const int base = blockIdx.x * 128;
    if (base >= cnt) return;

    const int tid = threadIdx.x;
    const int w = tid >> 6, l = tid & 63;
    const int l4 = l >> 4, l15 = l & 15;

    // ---- A preload (hi+lo) via row indirection
    shortx8 Ah[2][8], Al[2][8];
#pragma unroll
    for (int mt = 0; mt < 2; mt++) {
        int j = base + w * 32 + mt * 16 + l15;
        int row = flagList1[j < cnt ? j : cnt - 1];
        const float* xp = X + (size_t)row * DIM + l4 * 8;
#pragma unroll
        for (int kt = 0; kt < 8; kt++) {
            shortx8 vh, vl;
#pragma unroll
            for (int c4 = 0; c4 < 2; c4++) {
                float4 p = *(const float4*)(xp + kt * 32 + c4 * 4);
                float f[4] = {p.x, p.y, p.z, p.w};
#pragma unroll
                for (int q = 0; q < 4; q++) {
                    unsigned short h = f2bf(f[q]);
                    vh[c4 * 4 + q] = (short)h;
                    vl[c4 * 4 + q] = (short)f2bf(f[q] - bf2f(h));
                }
            }
            Ah[mt][kt] = vh; Al[mt][kt] = vl;
        }
    }

    const int sc = tid & 31;
    const int sseg = tid >> 5;
    uint4 sh0, sh1, sh2, sh3, sl0, sl1, sl2, sl3;
    {   // prologue: stage tile 0
        const uint4* sH = (const uint4*)(EbH + (size_t)sc * DIM + sseg * 32);
        const uint4* sL = (const uint4*)(EbL + (size_t)sc * DIM + sseg * 32);
        sh0 = sH[0]; sh1 = sH[1]; sh2 = sH[2]; sh3 = sH[3];
        sl0 = sL[0]; sl1 = sL[1]; sl2 = sL[2]; sl3 = sL[3];
        uint4* dH = (uint4*)&BsH[0][sc][sseg * 32];
        dH[0] = sh0; dH[1] = sh1; dH[2] = sh2; dH[3] = sh3;
        uint4* dL = (uint4*)&BsL[0][sc][sseg * 32];
        dL[0] = sl0; dL[1] = sl1; dL[2] = sl2; dL[3] = sl3;
    }

    unsigned long long best[8];
    unsigned bsec[8];
#pragma unroll
    for (int i = 0; i < 8; i++) { best[i] = ~0ull; bsec[i] = 0xFFFFFFFFu; }

    for (int ct = 0; ct < 32; ct++) {
        const int cur = ct & 1, nxt = cur ^ 1;
        __syncthreads();
        bool doNext = (ct + 1 < 32);
        if (doNext) {
            const uint4* sH = (const uint4*)(EbH + (size_t)((ct + 1) * 32 + sc) * DIM + sseg * 32);
            const uint4* sL = (const uint4*)(EbL + (size_t)((ct + 1) * 32 + sc) * DIM + sseg * 32);
            sh0 = sH[0]; sh1 = sH[1]; sh2 = sH[2]; sh3 = sH[3];
            sl0 = sL[0]; sl1 = sL[1]; sl2 = sL[2]; sl3 = sL[3];
        }
        float en0 = en[ct * 32 + l15];
        float en1 = en[ct * 32 + 16 + l15];

        floatx4 acc[2][2];
#pragma unroll
        for (int mt = 0; mt < 2; mt++)
#pragma unroll
            for (int nt = 0; nt < 2; nt++)
                acc[mt][nt] = (floatx4){0.f, 0.f, 0.f, 0.f};

#pragma unroll
        for (int kt = 0; kt < 8; kt++) {
            shortx8 bh0 = *(const shortx8*)&BsH[cur][l15][kt * 32 + l4 * 8];
            shortx8 bh1 = *(const shortx8*)&BsH[cur][16 + l15][kt * 32 + l4 * 8];
            shortx8 bl0 = *(const shortx8*)&BsL[cur][l15][kt * 32 + l4 * 8];
            shortx8 bl1 = *(const shortx8*)&BsL[cur][16 + l15][kt * 32 + l4 * 8];
#pragma unroll
            for (int mt = 0; mt < 2; mt++) {
                acc[mt][0] = __builtin_amdgcn_mfma_f32_16x16x32_bf16(Ah[mt][kt], bh0, acc[mt][0], 0, 0, 0);
                acc[mt][0] = __builtin_amdgcn_mfma_f32_16x16x32_bf16(Ah[mt][kt], bl0, acc[mt][0], 0, 0, 0);
                acc[mt][0] = __builtin_amdgcn_mfma_f32_16x16x32_bf16(Al[mt][kt], bh0, acc[mt][0], 0, 0, 0);
                acc[mt][1] = __builtin_amdgcn_mfma_f32_16x16x32_bf16(Ah[mt][kt], bh1, acc[mt][1], 0, 0, 0);
                acc[mt][1] = __builtin_amdgcn_mfma_f32_16x16x32_bf16(Ah[mt][kt], bl1, acc[mt][1], 0, 0, 0);
                acc[mt][1] = __builtin_amdgcn_mfma_f32_16x16x32_bf16(Al[mt][kt], bh1, acc[mt][1], 0, 0, 0);
            }
        }

#pragma unroll
        for (int mt = 0; mt < 2; mt++)
#pragma unroll
            for (int nt = 0; nt < 2; nt++) {
                float enc = nt ? en1 : en0;
                unsigned code = (unsigned)(ct * 32 + nt * 16 + l15);
#pragma unroll
                for (int r = 0; r < 4; r++) {
                    float s = fmaf(-2.0f, acc[mt][nt][r], enc);
                    unsigned m = fmap(s);
                    unsigned long long p = ((unsigned long long)m << 32) | code;
                    int sl = mt * 4 + r;
                    if (p < best[sl]) {
                        bsec[sl] = UMIN(bsec[sl], (unsigned)(best[sl] >> 32));
                        best[sl] = p;
                    } else {
                        bsec[sl] = UMIN(bsec[sl], m);
                    }
                }
            }

        if (doNext) {
            uint4* dH = (uint4*)&BsH[nxt][sc][sseg * 32];
            dH[0] = sh0; dH[1] = sh1; dH[2] = sh2; dH[3] = sh3;
            uint4* dL = (uint4*)&BsL[nxt][sc][sseg * 32];
            dL[0] = sl0; dL[1] = sl1; dL[2] = sl2; dL[3] = sl3;
        }
    }

    __syncthreads();
    unsigned long long* V = (unsigned long long*)&BsH[0][0][0];
    unsigned* W = (unsigned*)(V + 2048);
#pragma unroll
    for (int sl = 0; sl < 8; sl++) {
        int mt = sl >> 2, r = sl & 3;
        int rl = mt * 16 + l4 * 4 + r;
        V[(w * 32 + rl) * 16 + l15] = best[sl];
        W[(w * 32 + rl) * 16 + l15] = bsec[sl];
    }
    __syncthreads();
    if (tid < 128 && base + tid < cnt) {
        unsigned long long b1 = ~0ull;
        unsigned b2 = 0xFFFFFFFFu;
        const unsigned long long* Vp = V + tid * 16;
        const unsigned* Wp = W + tid * 16;
#pragma unroll
        for (int i = 0; i < 16; i++) {
            unsigned long long v = Vp[i];
            unsigned wv = Wp[i];
            if (v < b1) {
                b2 = UMIN(b2, (unsigned)(b1 >> 32));
                b1 = v;
                b2 = UMIN(b2, wv);
            } else {
                b2 = UMIN(b2, (unsigned)(v >> 32));
            }
        }
        int row = flagList1[base + tid];
        packed[row] = b1;
        float s1 = funmap((unsigned)(b1 >> 32));
        float s2 = funmap(b2);
        if (s2 - s1 < MARGIN2) {
            int pos = atomicAdd(&flagCnt[1], 1);
            if (pos < FCAP2) flagList2[pos] = row;
        }
    }
}

// ---------------------------------------------------------------------------
// Kernel 4 (pass3): exact fp32 re-solve for pass2-flagged rows (~O(10)).
// R4 version was a latency disaster (292 us, VALUBusy~0): per-thread private
// E rows -> 64-way divergent loads, ~16 blocks, nothing to hide latency.
// Now: E staged through LDS in 64-code tiles with flat-coalesced float4
// loads; threads 0..63 each run the IDENTICAL sequential-d fmaf chain
// (same summation order as the R4-passing kernel -> same winners), same
// np-rounded score s = fmaf(-2,dot,xn+en) and packed-u64 first-index ties.
// ---------------------------------------------------------------------------
__global__ void __launch_bounds__(256) vq_pass3(const float* __restrict__ X,
                                                const float* __restrict__ E,
                                                const float* __restrict__ xn,
                                                const float* __restrict__ en,
                                                unsigned long long* __restrict__ packed,
                                                const int* __restrict__ flagCnt2,
                                                const int* __restrict__ flagList2) {
    __shared__ float Et[64][257];   // 64 codes x 256 dims, +1 pad
    __shared__ float xs[256];
    __shared__ unsigned long long red[64];
    int cnt = *flagCnt2;
    if (cnt > FCAP2) cnt = FCAP2;
    const int tid = threadIdx.x;

    for (int it = blockIdx.x; it < cnt; it += gridDim.x) {
        int row = flagList2[it];
        __syncthreads();   // protect xs/red reuse across it-iterations
        if (tid < 64)
            *(float4*)&xs[tid * 4] = *(const float4*)&X[(size_t)row * DIM + tid * 4];
        float xnr = xn[row];
        unsigned long long bl = ~0ull;
        for (int t = 0; t < KC / 64; t++) {
            __syncthreads();
            {   // flat-coalesced tile load: 64 codes x 256 f32 = 4096 float4
                int f4 = tid;               // + 256*q
#pragma unroll
                for (int q = 0; q < 16; q++, f4 += 256) {
                    int code = f4 >> 6;     // 64 float4 per row
                    int off4 = f4 & 63;
                    *(float4*)&Et[code][off4 * 4] =
                        *(const float4*)(E + ((size_t)(t * 64 + code) * DIM) + off4 * 4);
                }
            }
            __syncthreads();
            if (tid < 64) {
                int c = t * 64 + tid;
                const float* er = Et[tid];
                float dot = 0.0f;
#pragma unroll
                for (int d = 0; d < 256; d += 4) {
                    dot = fmaf(xs[d + 0], er[d + 0], dot);
                    dot = fmaf(xs[d + 1], er[d + 1], dot);
                    dot = fmaf(xs[d + 2], er[d + 2], dot);
                    dot = fmaf(xs[d + 3], er[d + 3], dot);
                }
                float s = fmaf(-2.0f, dot, xnr + en[c]);   // matches np rounding
                unsigned long long p =
                    ((unsigned long long)__float_as_uint(s) << 32) | (unsigned)c;
                if (p < bl) bl = p;
            }
        }
        if (tid < 64) red[tid] = bl;
        __syncthreads();
        if (tid == 0) {
            unsigned long long m = red[0];
#pragma unroll
            for (int i = 1; i < 64; i++)
                if (red[i] < m) m = red[i];
            packed[row] = m;
        }
    }
}

// ---------------------------------------------------------------------------
// Kernel 5: gather quantized rows + fused squared-diff partial sums.
// ---------------------------------------------------------------------------
__global__ void __launch_bounds__(256) vq_gather(const float* __restrict__ X,
                                                 const float* __restrict__ E,
                                                 const unsigned long long* __restrict__ packed,
                                                 float* __restrict__ out,
                                                 float* __restrict__ accum) {
    const int tid = threadIdx.x;
    const int wave = tid >> 6;
    const int lane = tid & 63;
    const size_t rowBase = (size_t)blockIdx.x * 16;
    float part = 0.0f;
#pragma unroll
    for (int rr = 0; rr < 4; rr++) {
        size_t row = rowBase + wave + rr * 4;
        int code = (int)(unsigned int)(packed[row] & 0xffffffffull);
        float4 q = ((const float4*)(E + (size_t)code * DIM))[lane];
        float4 xv = ((const float4*)(X + row * DIM))[lane];
        ((float4*)(out + row * DIM))[lane] = q;
        float dx = q.x - xv.x, dy = q.y - xv.y, dz = q.z - xv.z, dw = q.w - xv.w;
        part = fmaf(dx, dx, part);
        part = fmaf(dy, dy, part);
        part = fmaf(dz, dz, part);
        part = fmaf(dw, dw, part);
    }
#pragma unroll
    for (int off = 1; off < 64; off <<= 1)
        part += __shfl_xor(part, off, 64);
    __shared__ float red[4];
    if ((tid & 63) == 0) red[tid >> 6] = part;
    __syncthreads();
    if (tid == 0) {
        float s = (red[0] + red[1]) + (red[2] + red[3]);
        atomicAdd(accum, s);
    }
}

// ---------------------------------------------------------------------------
// Kernel 6: finalize scalar loss. mean = sum / 2^24 (exact), loss = 2*mean.
// ---------------------------------------------------------------------------
__global__ void vq_finalize(const float* __restrict__ accum,
                            float* __restrict__ loss) {
    float m = *accum * (1.0f / 16777216.0f);
    *loss = m + m;
}

extern "C" void kernel_launch(void* const* d_in, const int* in_sizes, int n_in,
                              void* d_out, int out_size, void* d_ws, size_t ws_size,
                              hipStream_t stream) {
    const float* X = (const float*)d_in[0];   // [65536, 256]
    const float* E = (const float*)d_in[1];   // [1024, 256]
    float* out = (float*)d_out;               // quantized [65536*256] + loss [1]

    char* ws = (char*)d_ws;
    float* xn = (float*)ws;                                           // 262144 B
    float* en = (float*)(ws + 262144);                                //   4096 B
    unsigned short* EbH = (unsigned short*)(ws + 266240);             // 524288 B
    unsigned short* EbL = (unsigned short*)(ws + 790528);             // 524288 B
    unsigned long long* packed = (unsigned long long*)(ws + 1314816); // 524288 B
    int* flagList1 = (int*)(ws + 1839104);                            //  65536 B
    int* flagList2 = (int*)(ws + 1904640);                            //  16384 B
    float* accum = (float*)(ws + 1921024);
    int* flagCnt = (int*)(ws + 1921028);                              // [cnt1, cnt2]

    vq_norms   <<<(NROWS + KC) / 4, 256, 0, stream>>>(X, E, xn, en, EbH, EbL, accum, flagCnt);
    vq_pass1   <<<NROWS / 128, 256, 0, stream>>>(X, EbH, en, packed, flagCnt, flagList1);
    vq_pass2   <<<FCAP1 / 128, 256, 0, stream>>>(X, EbH, EbL, en, packed, flagCnt, flagList1, flagList2);
    vq_pass3   <<<64, 256, 0, stream>>>(X, E, xn, en, packed, flagCnt + 1, flagList2);
    vq_gather  <<<NROWS / 16, 256, 0, stream>>>(X, E, packed, out, accum);
    vq_finalize<<<1, 1, 0, stream>>>(accum, out + (size_t)NROWS * DIM);
}